// Round 2
// baseline (147.968 us; speedup 1.0000x reference)
//
#include <hip/hip_runtime.h>

// B=16, N=1024, D=512, DIRECTIONS=2
#define NB 16
#define NN 1024
#define ND 512

typedef __attribute__((ext_vector_type(8))) short short8;   // 8 x bf16
typedef __attribute__((ext_vector_type(4))) float f32x4;

typedef const __attribute__((address_space(1))) void* gptr1;
typedef __attribute__((address_space(3))) void* lptr3;

#define VMCNT0() asm volatile("s_waitcnt vmcnt(0)" ::: "memory")
#define LGKM0()  asm volatile("s_waitcnt lgkmcnt(0)" ::: "memory")
#define BAR()    __builtin_amdgcn_s_barrier()

static __device__ __forceinline__ unsigned f2bf(float f) {
  union { float f; unsigned u; } v; v.f = f;
  unsigned r = v.u + 0x7FFFu + ((v.u >> 16) & 1u);   // RNE
  return r >> 16;
}

// ---------------- k_wt: W [1024][512] f32 -> WT [512][1024] bf16 -------------
__global__ void k_wt(const float* __restrict__ W, unsigned short* __restrict__ WT) {
  __shared__ float t[64][65];
  int r0 = blockIdx.x * 64;   // over 1024 rows of W (k dim)
  int c0 = blockIdx.y * 64;   // over 512 cols (d dim)
  int tid = threadIdx.x;
#pragma unroll
  for (int i = 0; i < 4; ++i) {
    int f = i * 256 + tid;
    int r = f >> 4, cq = f & 15;
    float4 v = *(const float4*)(W + (size_t)(r0 + r) * ND + c0 + cq * 4);
    t[r][cq * 4 + 0] = v.x; t[r][cq * 4 + 1] = v.y;
    t[r][cq * 4 + 2] = v.z; t[r][cq * 4 + 3] = v.w;
  }
  __syncthreads();
#pragma unroll
  for (int i = 0; i < 8; ++i) {
    int f = i * 256 + tid;
    int oc = f >> 5;            // 0..63 output row (d)
    int on = (f & 31) * 2;      // 0..62 output col (k), pair
    unsigned lo = f2bf(t[on][oc]), hi = f2bf(t[on + 1][oc]);
    *(unsigned*)(WT + (size_t)(c0 + oc) * NN + r0 + on) = lo | (hi << 16);
  }
}

// -------- k_pre: Pt_j[b][d][m] = bf16( sum_c W[j*512+c][d] * hid[b][m][c] ) --
// Per batch: M=512 (d), N=1024 (m), K=512 (c). BM=128 BN=128 BK=64.
// A_j = WT rows (global_load_lds, pre-swizzled src); B = hid rows (reg-stage+cast).
__global__ __launch_bounds__(256, 2) void k_pre(
    const float* __restrict__ hid, const unsigned short* __restrict__ WT,
    unsigned short* __restrict__ Pt1, unsigned short* __restrict__ Pt2) {
  __shared__ __align__(16) char smem[49152];
  char* A1 = smem;           // WT j=0 tile [128 d][64 c]
  char* A2 = smem + 16384;   // WT j=1 tile
  char* Bh = smem + 32768;   // hid tile [128 m][64 c]

  int phys = blockIdx.x;                      // 512 blocks, %8==0
  int logical = (phys & 7) * 64 + (phys >> 3);
  int b = logical >> 5;
  int rem = logical & 31;
  int dt = rem >> 3, mt = rem & 7;
  int d0 = dt * 128, m0 = mt * 128;

  int tid = threadIdx.x, lane = tid & 63, wid = tid >> 6;
  int wr = wid >> 1, wc = wid & 1;

  const float* hb = hid + (size_t)b * NN * ND;

  f32x4 acc1[4][4], acc2[4][4];
  f32x4 zero = {0.f, 0.f, 0.f, 0.f};
#pragma unroll
  for (int i = 0; i < 4; ++i)
#pragma unroll
    for (int j = 0; j < 4; ++j) { acc1[i][j] = zero; acc2[i][j] = zero; }

  float4 fc[8], fn[8];
  // prologue: hid regs for kt=0, A-tiles for kt=0
#pragma unroll
  for (int it = 0; it < 8; ++it) {
    int f = it * 256 + tid;
    fc[it] = *(const float4*)(hb + (size_t)(m0 + (f >> 4)) * ND + (f & 15) * 4);
  }
#pragma unroll
  for (int i = 0; i < 4; ++i) {
    int q = wid * 4 + i;
    int r = q * 8 + (lane >> 3);
    int sl = (lane & 7) ^ (r & 7);
    __builtin_amdgcn_global_load_lds((gptr1)(WT + (size_t)(d0 + r) * NN + sl * 8),
                                     (lptr3)(A1 + q * 1024), 16, 0, 0);
    __builtin_amdgcn_global_load_lds((gptr1)(WT + (size_t)(d0 + r) * NN + 512 + sl * 8),
                                     (lptr3)(A2 + q * 1024), 16, 0, 0);
  }

  for (int kt = 0; kt < 8; ++kt) {
    int k0 = kt * 64;
    // convert hid regs -> Bh (swizzled)
#pragma unroll
    for (int it = 0; it < 8; ++it) {
      int f = it * 256 + tid;
      int row = f >> 4, colq = f & 15;
      float4 v = fc[it];
      unsigned lo = f2bf(v.x) | (f2bf(v.y) << 16);
      unsigned hi = f2bf(v.z) | (f2bf(v.w) << 16);
      int addr = row * 128 + (((colq >> 1) ^ (row & 7)) * 16) + (colq & 1) * 8;
      *(uint2*)(Bh + addr) = make_uint2(lo, hi);
    }
    VMCNT0();                         // A1/A2 DMA (issued prev iter) arrived
    if (kt < 7) {
#pragma unroll
      for (int it = 0; it < 8; ++it) {
        int f = it * 256 + tid;
        fn[it] = *(const float4*)(hb + (size_t)(m0 + (f >> 4)) * ND + k0 + 64 + (f & 15) * 4);
      }
    }
    LGKM0();
    BAR();
    // MFMA phase
#pragma unroll
    for (int ks = 0; ks < 2; ++ks) {
      short8 a1[4], a2[4], bf[4];
#pragma unroll
      for (int mi = 0; mi < 4; ++mi) {
        int row = wr * 64 + mi * 16 + (lane & 15);
        int slot = (ks * 4 + (lane >> 4)) ^ (row & 7);
        a1[mi] = *(const short8*)(A1 + row * 128 + slot * 16);
        a2[mi] = *(const short8*)(A2 + row * 128 + slot * 16);
      }
#pragma unroll
      for (int nj = 0; nj < 4; ++nj) {
        int col = wc * 64 + nj * 16 + (lane & 15);
        int slot = (ks * 4 + (lane >> 4)) ^ (col & 7);
        bf[nj] = *(const short8*)(Bh + col * 128 + slot * 16);
      }
#pragma unroll
      for (int mi = 0; mi < 4; ++mi)
#pragma unroll
        for (int nj = 0; nj < 4; ++nj) {
          acc1[mi][nj] = __builtin_amdgcn_mfma_f32_16x16x32_bf16(a1[mi], bf[nj], acc1[mi][nj], 0, 0, 0);
          acc2[mi][nj] = __builtin_amdgcn_mfma_f32_16x16x32_bf16(a2[mi], bf[nj], acc2[mi][nj], 0, 0, 0);
        }
    }
    BAR();
    if (kt < 7) {
      // issue A-tiles for kt+1 (in flight across next conversion)
#pragma unroll
      for (int i = 0; i < 4; ++i) {
        int q = wid * 4 + i;
        int r = q * 8 + (lane >> 3);
        int sl = (lane & 7) ^ (r & 7);
        __builtin_amdgcn_global_load_lds((gptr1)(WT + (size_t)(d0 + r) * NN + k0 + 64 + sl * 8),
                                         (lptr3)(A1 + q * 1024), 16, 0, 0);
        __builtin_amdgcn_global_load_lds((gptr1)(WT + (size_t)(d0 + r) * NN + 512 + k0 + 64 + sl * 8),
                                         (lptr3)(A2 + q * 1024), 16, 0, 0);
      }
#pragma unroll
      for (int it = 0; it < 8; ++it) fc[it] = fn[it];
    }
  }
  // epilogue: Pt_j[b][d][m] bf16
  unsigned short* P1b = Pt1 + (size_t)b * ND * NN;
  unsigned short* P2b = Pt2 + (size_t)b * ND * NN;
#pragma unroll
  for (int mi = 0; mi < 4; ++mi) {
#pragma unroll
    for (int rr = 0; rr < 4; ++rr) {
      int rowd = d0 + wr * 64 + mi * 16 + (lane >> 4) * 4 + rr;
#pragma unroll
      for (int nj = 0; nj < 4; ++nj) {
        int colm = m0 + wc * 64 + nj * 16 + (lane & 15);
        P1b[(size_t)rowd * NN + colm] = (unsigned short)f2bf(acc1[mi][nj][rr]);
        P2b[(size_t)rowd * NN + colm] = (unsigned short)f2bf(acc2[mi][nj][rr]);
      }
    }
  }
}

// -------- k_main: out[n][d] = relu(i1*(M1@Pt1)[n][d] + i2*(M2@Pt2)[n][d] + bias[d]) + hid[n][d]
// Per batch: M=1024 (n), N=512 (d), K=1024 (m). BM=128 BN=128 BK=64.
// Counts via cnt = mfma(mask, ones, cnt) — no separate adj pass.
__global__ __launch_bounds__(256, 2) void k_main(
    const int* __restrict__ adj, const unsigned short* __restrict__ Pt1,
    const unsigned short* __restrict__ Pt2, const float* __restrict__ bias,
    const float* __restrict__ hid, float* __restrict__ out) {
  __shared__ __align__(16) char smem[65536];
  char* A1 = smem;            // mask1 tile [128 n][64 m]
  char* A2 = smem + 16384;    // mask2 tile
  char* B1 = smem + 32768;    // Pt1 tile [128 d][64 m]
  char* B2 = smem + 49152;    // Pt2 tile

  int phys = blockIdx.x;
  int logical = (phys & 7) * 64 + (phys >> 3);
  int b = logical >> 5;
  int rem = logical & 31;
  int mt = rem >> 2, nt = rem & 3;
  int n0 = mt * 128, d0 = nt * 128;

  int tid = threadIdx.x, lane = tid & 63, wid = tid >> 6;
  int wr = wid >> 1, wc = wid & 1;

  const int* adjb = adj + (size_t)b * NN * NN;
  const unsigned short* P1b = Pt1 + (size_t)b * ND * NN;
  const unsigned short* P2b = Pt2 + (size_t)b * ND * NN;

  f32x4 acc1[4][4], acc2[4][4], cnt1[4], cnt2[4];
  f32x4 zero = {0.f, 0.f, 0.f, 0.f};
#pragma unroll
  for (int i = 0; i < 4; ++i) {
    cnt1[i] = zero; cnt2[i] = zero;
#pragma unroll
    for (int j = 0; j < 4; ++j) { acc1[i][j] = zero; acc2[i][j] = zero; }
  }
  short8 ones;
#pragma unroll
  for (int i = 0; i < 8; ++i) ones[i] = (short)0x3F80;

  int4 vc[8], vn[8];
  // prologue: adj regs for kt=0, B-tiles for kt=0
#pragma unroll
  for (int it = 0; it < 8; ++it) {
    int f = it * 256 + tid;
    vc[it] = *(const int4*)(adjb + (size_t)(n0 + (f >> 4)) * NN + (f & 15) * 4);
  }
#pragma unroll
  for (int i = 0; i < 4; ++i) {
    int q = wid * 4 + i;
    int r = q * 8 + (lane >> 3);
    int sl = (lane & 7) ^ (r & 7);
    __builtin_amdgcn_global_load_lds((gptr1)(P1b + (size_t)(d0 + r) * NN + sl * 8),
                                     (lptr3)(B1 + q * 1024), 16, 0, 0);
    __builtin_amdgcn_global_load_lds((gptr1)(P2b + (size_t)(d0 + r) * NN + sl * 8),
                                     (lptr3)(B2 + q * 1024), 16, 0, 0);
  }

  for (int kt = 0; kt < 16; ++kt) {
    int k0 = kt * 64;
    // convert adj regs -> mask tiles (swizzled ds_write)
#pragma unroll
    for (int it = 0; it < 8; ++it) {
      int f = it * 256 + tid;
      int row = f >> 4, colq = f & 15;
      int4 v = vc[it];
      unsigned m1a = (v.x == 1 ? 0x3F80u : 0u) | (v.y == 1 ? 0x3F800000u : 0u);
      unsigned m1b = (v.z == 1 ? 0x3F80u : 0u) | (v.w == 1 ? 0x3F800000u : 0u);
      unsigned m2a = (v.x == 2 ? 0x3F80u : 0u) | (v.y == 2 ? 0x3F800000u : 0u);
      unsigned m2b = (v.z == 2 ? 0x3F80u : 0u) | (v.w == 2 ? 0x3F800000u : 0u);
      int addr = row * 128 + (((colq >> 1) ^ (row & 7)) * 16) + (colq & 1) * 8;
      *(uint2*)(A1 + addr) = make_uint2(m1a, m1b);
      *(uint2*)(A2 + addr) = make_uint2(m2a, m2b);
    }
    VMCNT0();                         // B1/B2 DMA (issued prev iter) arrived
    if (kt < 15) {
#pragma unroll
      for (int it = 0; it < 8; ++it) {
        int f = it * 256 + tid;
        vn[it] = *(const int4*)(adjb + (size_t)(n0 + (f >> 4)) * NN + k0 + 64 + (f & 15) * 4);
      }
    }
    LGKM0();
    BAR();
    // MFMA phase: 2 k-substeps; per dir: 16 acc MFMAs + 4 cnt MFMAs
#pragma unroll
    for (int ks = 0; ks < 2; ++ks) {
      short8 a1[4], a2[4], b1[4], b2[4];
#pragma unroll
      for (int mi = 0; mi < 4; ++mi) {
        int row = wr * 64 + mi * 16 + (lane & 15);
        int slot = (ks * 4 + (lane >> 4)) ^ (row & 7);
        a1[mi] = *(const short8*)(A1 + row * 128 + slot * 16);
        a2[mi] = *(const short8*)(A2 + row * 128 + slot * 16);
      }
#pragma unroll
      for (int nj = 0; nj < 4; ++nj) {
        int col = wc * 64 + nj * 16 + (lane & 15);
        int slot = (ks * 4 + (lane >> 4)) ^ (col & 7);
        b1[nj] = *(const short8*)(B1 + col * 128 + slot * 16);
        b2[nj] = *(const short8*)(B2 + col * 128 + slot * 16);
      }
#pragma unroll
      for (int mi = 0; mi < 4; ++mi) {
        cnt1[mi] = __builtin_amdgcn_mfma_f32_16x16x32_bf16(a1[mi], ones, cnt1[mi], 0, 0, 0);
        cnt2[mi] = __builtin_amdgcn_mfma_f32_16x16x32_bf16(a2[mi], ones, cnt2[mi], 0, 0, 0);
#pragma unroll
        for (int nj = 0; nj < 4; ++nj) {
          acc1[mi][nj] = __builtin_amdgcn_mfma_f32_16x16x32_bf16(a1[mi], b1[nj], acc1[mi][nj], 0, 0, 0);
          acc2[mi][nj] = __builtin_amdgcn_mfma_f32_16x16x32_bf16(a2[mi], b2[nj], acc2[mi][nj], 0, 0, 0);
        }
      }
    }
    BAR();
    if (kt < 15) {
      // issue B-tiles for kt+1 (latency hides under next conversion)
#pragma unroll
      for (int i = 0; i < 4; ++i) {
        int q = wid * 4 + i;
        int r = q * 8 + (lane >> 3);
        int sl = (lane & 7) ^ (r & 7);
        __builtin_amdgcn_global_load_lds((gptr1)(P1b + (size_t)(d0 + r) * NN + k0 + 64 + sl * 8),
                                         (lptr3)(B1 + q * 1024), 16, 0, 0);
        __builtin_amdgcn_global_load_lds((gptr1)(P2b + (size_t)(d0 + r) * NN + k0 + 64 + sl * 8),
                                         (lptr3)(B2 + q * 1024), 16, 0, 0);
      }
#pragma unroll
      for (int it = 0; it < 8; ++it) vc[it] = vn[it];
    }
  }
  // epilogue: combine directions, bias, relu, residual; write pre-LN f32
#pragma unroll
  for (int mi = 0; mi < 4; ++mi) {
#pragma unroll
    for (int rr = 0; rr < 4; ++rr) {
      int n = n0 + wr * 64 + mi * 16 + (lane >> 4) * 4 + rr;
      float i1 = 1.0f / (cnt1[mi][rr] + 1e-13f);
      float i2 = 1.0f / (cnt2[mi][rr] + 1e-13f);
      const float* hrow = hid + ((size_t)b * NN + n) * ND;
      float* orow = out + ((size_t)b * NN + n) * ND;
#pragma unroll
      for (int nj = 0; nj < 4; ++nj) {
        int d = d0 + wc * 64 + nj * 16 + (lane & 15);
        float v = acc1[mi][nj][rr] * i1 + acc2[mi][nj][rr] * i2 + bias[d];
        v = fmaxf(v, 0.f);
        orow[d] = v + hrow[d];
      }
    }
  }
}

// ---------------- k_ln: in-place rowwise LayerNorm on d_out ------------------
__global__ void k_ln(float* __restrict__ out, const float* __restrict__ gamma,
                     const float* __restrict__ beta) {
  int row = blockIdx.x * 4 + (threadIdx.x >> 6);
  int lane = threadIdx.x & 63;
  float* p = out + (size_t)row * ND;
  float4 x0 = *(const float4*)(p + lane * 4);
  float4 x1 = *(const float4*)(p + 256 + lane * 4);
  float s = x0.x + x0.y + x0.z + x0.w + x1.x + x1.y + x1.z + x1.w;
#pragma unroll
  for (int o = 32; o; o >>= 1) s += __shfl_xor(s, o);
  float mu = s * (1.0f / 512.0f);
  float d0x = x0.x - mu, d0y = x0.y - mu, d0z = x0.z - mu, d0w = x0.w - mu;
  float d1x = x1.x - mu, d1y = x1.y - mu, d1z = x1.z - mu, d1w = x1.w - mu;
  float v = d0x * d0x + d0y * d0y + d0z * d0z + d0w * d0w
          + d1x * d1x + d1y * d1y + d1z * d1z + d1w * d1w;
#pragma unroll
  for (int o = 32; o; o >>= 1) v += __shfl_xor(v, o);
  float rs = rsqrtf(v * (1.0f / 512.0f) + 1e-5f);
  float4 g0 = *(const float4*)(gamma + lane * 4);
  float4 g1 = *(const float4*)(gamma + 256 + lane * 4);
  float4 b0 = *(const float4*)(beta + lane * 4);
  float4 b1 = *(const float4*)(beta + 256 + lane * 4);
  float4 y0, y1;
  y0.x = d0x * rs * g0.x + b0.x; y0.y = d0y * rs * g0.y + b0.y;
  y0.z = d0z * rs * g0.z + b0.z; y0.w = d0w * rs * g0.w + b0.w;
  y1.x = d1x * rs * g1.x + b1.x; y1.y = d1y * rs * g1.y + b1.y;
  y1.z = d1z * rs * g1.z + b1.z; y1.w = d1w * rs * g1.w + b1.w;
  *(float4*)(p + lane * 4) = y0;
  *(float4*)(p + 256 + lane * 4) = y1;
}

extern "C" void kernel_launch(void* const* d_in, const int* in_sizes, int n_in,
                              void* d_out, int out_size, void* d_ws, size_t ws_size,
                              hipStream_t stream) {
  (void)in_sizes; (void)n_in; (void)out_size; (void)ws_size;
  const int*   adj   = (const int*)d_in[0];
  const float* hid   = (const float*)d_in[1];
  const float* W     = (const float*)d_in[2];
  const float* bias  = (const float*)d_in[3];
  const float* gamma = (const float*)d_in[4];
  const float* beta  = (const float*)d_in[5];
  float* out = (float*)d_out;

  char* ws = (char*)d_ws;
  unsigned short* WT  = (unsigned short*)ws;                 // 512*1024*2 = 1 MiB
  unsigned short* Pt1 = (unsigned short*)(ws + 1048576);     // 16*512*1024*2 = 16 MiB
  unsigned short* Pt2 = (unsigned short*)(ws + 17825792);    // 16 MiB  (total ~33 MiB)

  k_wt  <<<dim3(16, 8), 256, 0, stream>>>(W, WT);
  k_pre <<<512, 256, 0, stream>>>(hid, WT, Pt1, Pt2);
  k_main<<<512, 256, 0, stream>>>(adj, Pt1, Pt2, bias, hid, out);
  k_ln  <<<4096, 256, 0, stream>>>(out, gamma, beta);
}

// Round 3
// 99.452 us; speedup vs baseline: 1.4878x; 1.4878x over previous
//
#include <hip/hip_runtime.h>

// B=16, N=1024, D=512, DIRECTIONS=2
#define NB 16
#define NN 1024
#define ND 512

typedef __attribute__((ext_vector_type(8))) short short8;   // 8 x bf16
typedef __attribute__((ext_vector_type(4))) float f32x4;

typedef const __attribute__((address_space(1))) void* gptr1;
typedef __attribute__((address_space(3))) void* lptr3;

#define VMCNT0() asm volatile("s_waitcnt vmcnt(0)" ::: "memory")
#define VMCNT1() asm volatile("s_waitcnt vmcnt(1)" ::: "memory")
#define LGKM0()  asm volatile("s_waitcnt lgkmcnt(0)" ::: "memory")
#define BAR()    __builtin_amdgcn_s_barrier()

static __device__ __forceinline__ unsigned f2bf(float f) {
  union { float f; unsigned u; } v; v.f = f;
  unsigned r = v.u + 0x7FFFu + ((v.u >> 16) & 1u);   // RNE
  return r >> 16;
}

// ---------------- k_wt: W [1024][512] f32 -> WT [512][1024] bf16 -------------
__global__ void k_wt(const float* __restrict__ W, unsigned short* __restrict__ WT) {
  __shared__ float t[64][65];
  int r0 = blockIdx.x * 64;   // over 1024 rows of W (k dim)
  int c0 = blockIdx.y * 64;   // over 512 cols (d dim)
  int tid = threadIdx.x;
#pragma unroll
  for (int i = 0; i < 4; ++i) {
    int f = i * 256 + tid;
    int r = f >> 4, cq = f & 15;
    float4 v = *(const float4*)(W + (size_t)(r0 + r) * ND + c0 + cq * 4);
    t[r][cq * 4 + 0] = v.x; t[r][cq * 4 + 1] = v.y;
    t[r][cq * 4 + 2] = v.z; t[r][cq * 4 + 3] = v.w;
  }
  __syncthreads();
#pragma unroll
  for (int i = 0; i < 8; ++i) {
    int f = i * 256 + tid;
    int oc = f >> 5;            // 0..63 output row (d)
    int on = (f & 31) * 2;      // 0..62 output col (k), pair
    unsigned lo = f2bf(t[on][oc]), hi = f2bf(t[on + 1][oc]);
    *(unsigned*)(WT + (size_t)(c0 + oc) * NN + r0 + on) = lo | (hi << 16);
  }
}

// -------- k_pack: adj int32 -> 2-bit codes (bit0: ==1, bit1: ==2) + counts ---
// packed[row][l] covers elems 16l..16l+15, elem j at bits 2j.
__global__ void k_pack(const int* __restrict__ adj, unsigned* __restrict__ packed,
                       float* __restrict__ invc) {
  int wid = threadIdx.x >> 6, lane = threadIdx.x & 63;
  int wrow0 = (blockIdx.x * 4 + wid) * 4;
#pragma unroll
  for (int r = 0; r < 4; ++r) {
    int row = wrow0 + r;
    const int* p = adj + (size_t)row * NN + lane * 16;
    unsigned u = 0;
#pragma unroll
    for (int i = 0; i < 4; ++i) {
      int4 v = *(const int4*)(p + i * 4);
      u |= ((unsigned)v.x << (8 * i)) | ((unsigned)v.y << (8 * i + 2))
         | ((unsigned)v.z << (8 * i + 4)) | ((unsigned)v.w << (8 * i + 6));
    }
    packed[(size_t)row * 64 + lane] = u;
    unsigned c1 = __popc(u & 0x55555555u);
    unsigned c2 = __popc(u & 0xAAAAAAAAu);
    unsigned pr = c1 | (c2 << 16);
#pragma unroll
    for (int o = 32; o; o >>= 1) pr += __shfl_xor(pr, o);
    if (lane == 0) {
      invc[row * 2 + 0] = 1.0f / ((float)(pr & 0xFFFFu) + 1e-13f);
      invc[row * 2 + 1] = 1.0f / ((float)(pr >> 16) + 1e-13f);
    }
  }
}

// -------- k_pre: Pt_j[b][d][m] = bf16( sum_c W[j*512+c][d] * hid[b][m][c] ) --
// Per batch: M=512 (d), N=1024 (m), K=512 (c). BM=128 BN=128 BK=64.  (proven)
__global__ __launch_bounds__(256, 2) void k_pre(
    const float* __restrict__ hid, const unsigned short* __restrict__ WT,
    unsigned short* __restrict__ Pt1, unsigned short* __restrict__ Pt2) {
  __shared__ __align__(16) char smem[49152];
  char* A1 = smem;           // WT j=0 tile [128 d][64 c]
  char* A2 = smem + 16384;   // WT j=1 tile
  char* Bh = smem + 32768;   // hid tile [128 m][64 c]

  int phys = blockIdx.x;
  int logical = (phys & 7) * 64 + (phys >> 3);
  int b = logical >> 5;
  int rem = logical & 31;
  int dt = rem >> 3, mt = rem & 7;
  int d0 = dt * 128, m0 = mt * 128;

  int tid = threadIdx.x, lane = tid & 63, wid = tid >> 6;
  int wr = wid >> 1, wc = wid & 1;

  const float* hb = hid + (size_t)b * NN * ND;

  f32x4 acc1[4][4], acc2[4][4];
  f32x4 zero = {0.f, 0.f, 0.f, 0.f};
#pragma unroll
  for (int i = 0; i < 4; ++i)
#pragma unroll
    for (int j = 0; j < 4; ++j) { acc1[i][j] = zero; acc2[i][j] = zero; }

  float4 fc[8], fn[8];
#pragma unroll
  for (int it = 0; it < 8; ++it) {
    int f = it * 256 + tid;
    fc[it] = *(const float4*)(hb + (size_t)(m0 + (f >> 4)) * ND + (f & 15) * 4);
  }
#pragma unroll
  for (int i = 0; i < 4; ++i) {
    int q = wid * 4 + i;
    int r = q * 8 + (lane >> 3);
    int sl = (lane & 7) ^ (r & 7);
    __builtin_amdgcn_global_load_lds((gptr1)(WT + (size_t)(d0 + r) * NN + sl * 8),
                                     (lptr3)(A1 + q * 1024), 16, 0, 0);
    __builtin_amdgcn_global_load_lds((gptr1)(WT + (size_t)(d0 + r) * NN + 512 + sl * 8),
                                     (lptr3)(A2 + q * 1024), 16, 0, 0);
  }

  for (int kt = 0; kt < 8; ++kt) {
    int k0 = kt * 64;
#pragma unroll
    for (int it = 0; it < 8; ++it) {
      int f = it * 256 + tid;
      int row = f >> 4, colq = f & 15;
      float4 v = fc[it];
      unsigned lo = f2bf(v.x) | (f2bf(v.y) << 16);
      unsigned hi = f2bf(v.z) | (f2bf(v.w) << 16);
      int addr = row * 128 + (((colq >> 1) ^ (row & 7)) * 16) + (colq & 1) * 8;
      *(uint2*)(Bh + addr) = make_uint2(lo, hi);
    }
    VMCNT0();
    if (kt < 7) {
#pragma unroll
      for (int it = 0; it < 8; ++it) {
        int f = it * 256 + tid;
        fn[it] = *(const float4*)(hb + (size_t)(m0 + (f >> 4)) * ND + k0 + 64 + (f & 15) * 4);
      }
    }
    LGKM0();
    BAR();
#pragma unroll
    for (int ks = 0; ks < 2; ++ks) {
      short8 a1[4], a2[4], bf[4];
#pragma unroll
      for (int mi = 0; mi < 4; ++mi) {
        int row = wr * 64 + mi * 16 + (lane & 15);
        int slot = (ks * 4 + (lane >> 4)) ^ (row & 7);
        a1[mi] = *(const short8*)(A1 + row * 128 + slot * 16);
        a2[mi] = *(const short8*)(A2 + row * 128 + slot * 16);
      }
#pragma unroll
      for (int nj = 0; nj < 4; ++nj) {
        int col = wc * 64 + nj * 16 + (lane & 15);
        int slot = (ks * 4 + (lane >> 4)) ^ (col & 7);
        bf[nj] = *(const short8*)(Bh + col * 128 + slot * 16);
      }
#pragma unroll
      for (int mi = 0; mi < 4; ++mi)
#pragma unroll
        for (int nj = 0; nj < 4; ++nj) {
          acc1[mi][nj] = __builtin_amdgcn_mfma_f32_16x16x32_bf16(a1[mi], bf[nj], acc1[mi][nj], 0, 0, 0);
          acc2[mi][nj] = __builtin_amdgcn_mfma_f32_16x16x32_bf16(a2[mi], bf[nj], acc2[mi][nj], 0, 0, 0);
        }
    }
    BAR();
    if (kt < 7) {
#pragma unroll
      for (int i = 0; i < 4; ++i) {
        int q = wid * 4 + i;
        int r = q * 8 + (lane >> 3);
        int sl = (lane & 7) ^ (r & 7);
        __builtin_amdgcn_global_load_lds((gptr1)(WT + (size_t)(d0 + r) * NN + k0 + 64 + sl * 8),
                                         (lptr3)(A1 + q * 1024), 16, 0, 0);
        __builtin_amdgcn_global_load_lds((gptr1)(WT + (size_t)(d0 + r) * NN + 512 + k0 + 64 + sl * 8),
                                         (lptr3)(A2 + q * 1024), 16, 0, 0);
      }
#pragma unroll
      for (int it = 0; it < 8; ++it) fc[it] = fn[it];
    }
    __builtin_amdgcn_sched_barrier(0);
  }
  unsigned short* P1b = Pt1 + (size_t)b * ND * NN;
  unsigned short* P2b = Pt2 + (size_t)b * ND * NN;
#pragma unroll
  for (int mi = 0; mi < 4; ++mi) {
#pragma unroll
    for (int rr = 0; rr < 4; ++rr) {
      int rowd = d0 + wr * 64 + mi * 16 + (lane >> 4) * 4 + rr;
#pragma unroll
      for (int nj = 0; nj < 4; ++nj) {
        int colm = m0 + wc * 64 + nj * 16 + (lane & 15);
        P1b[(size_t)rowd * NN + colm] = (unsigned short)f2bf(acc1[mi][nj][rr]);
        P2b[(size_t)rowd * NN + colm] = (unsigned short)f2bf(acc2[mi][nj][rr]);
      }
    }
  }
}

// -------- k_main: out[n][d] = relu(i1*(M1@Pt1) + i2*(M2@Pt2) + bias) + hid ---
// Per batch: M=1024 (n), N=512 (d), K=1024 (m). BM=128 BN=128 BK=64.
// Masks unpacked on the fly from 2-bit codes (8B/thread/kt, L2-resident).
__global__ __launch_bounds__(256, 2) void k_main(
    const unsigned* __restrict__ packed, const unsigned short* __restrict__ Pt1,
    const unsigned short* __restrict__ Pt2, const float* __restrict__ invc,
    const float* __restrict__ bias, const float* __restrict__ hid,
    float* __restrict__ out) {
  __shared__ __align__(16) char smem[65536];
  char* A1 = smem;            // mask1 tile [128 n][64 m] bf16 swizzled
  char* A2 = smem + 16384;    // mask2 tile
  char* B1 = smem + 32768;    // Pt1 tile [128 d][64 m]
  char* B2 = smem + 49152;    // Pt2 tile

  int phys = blockIdx.x;
  int logical = (phys & 7) * 64 + (phys >> 3);
  int b = logical >> 5;
  int rem = logical & 31;
  int mt = rem >> 2, nt = rem & 3;
  int n0 = mt * 128, d0 = nt * 128;

  int tid = threadIdx.x, lane = tid & 63, wid = tid >> 6;
  int wr = wid >> 1, wc = wid & 1;
  int row = tid >> 1, half = tid & 1;       // conversion ownership: 32 elems

  const unsigned* pkb = packed + ((size_t)b * NN + n0 + row) * 64 + half * 2;
  const unsigned short* P1b = Pt1 + (size_t)b * ND * NN;
  const unsigned short* P2b = Pt2 + (size_t)b * ND * NN;

  f32x4 acc1[4][4], acc2[4][4];
  f32x4 zero = {0.f, 0.f, 0.f, 0.f};
#pragma unroll
  for (int i = 0; i < 4; ++i)
#pragma unroll
    for (int j = 0; j < 4; ++j) { acc1[i][j] = zero; acc2[i][j] = zero; }

  uint2 pc, pn;
  pc = *(const uint2*)pkb;                       // kt=0 codes
#pragma unroll
  for (int i = 0; i < 4; ++i) {                  // B DMAs for kt=0
    int q = wid * 4 + i;
    int r = q * 8 + (lane >> 3);
    int sl = (lane & 7) ^ (r & 7);
    __builtin_amdgcn_global_load_lds((gptr1)(P1b + (size_t)(d0 + r) * NN + sl * 8),
                                     (lptr3)(B1 + q * 1024), 16, 0, 0);
    __builtin_amdgcn_global_load_lds((gptr1)(P2b + (size_t)(d0 + r) * NN + sl * 8),
                                     (lptr3)(B2 + q * 1024), 16, 0, 0);
  }
  __builtin_amdgcn_sched_barrier(0);

  for (int kt = 0; kt < 16; ++kt) {
    int k0 = kt * 64;
    // ---- unpack 2-bit codes -> bf16 mask tiles (8 x ds_write_b128)
#pragma unroll
    for (int g = 0; g < 4; ++g) {
      unsigned w = (g < 2) ? pc.x : pc.y;
      unsigned bits = w >> ((g & 1) * 16);       // 8 elems in low 16 bits
      uint4 u1, u2;
      unsigned t0 = bits, t1 = bits >> 4, t2 = bits >> 8, t3 = bits >> 12;
      u1.x = (t0 & 1) * 0x3F80u | ((t0 >> 2) & 1) * 0x3F800000u;
      u2.x = ((t0 >> 1) & 1) * 0x3F80u | ((t0 >> 3) & 1) * 0x3F800000u;
      u1.y = (t1 & 1) * 0x3F80u | ((t1 >> 2) & 1) * 0x3F800000u;
      u2.y = ((t1 >> 1) & 1) * 0x3F80u | ((t1 >> 3) & 1) * 0x3F800000u;
      u1.z = (t2 & 1) * 0x3F80u | ((t2 >> 2) & 1) * 0x3F800000u;
      u2.z = ((t2 >> 1) & 1) * 0x3F80u | ((t2 >> 3) & 1) * 0x3F800000u;
      u1.w = (t3 & 1) * 0x3F80u | ((t3 >> 2) & 1) * 0x3F800000u;
      u2.w = ((t3 >> 1) & 1) * 0x3F80u | ((t3 >> 3) & 1) * 0x3F800000u;
      int slot = half * 4 + g;
      int addr = row * 128 + ((slot ^ (row & 7)) * 16);
      *(uint4*)(A1 + addr) = u1;
      *(uint4*)(A2 + addr) = u2;
    }
    if (kt < 15) {
      pn = *(const uint2*)(pkb + (kt + 1) * 4);  // next codes (L2, 1 inst)
      VMCNT1();                                  // drain 8 B-DMAs, keep pn in flight
    } else {
      VMCNT0();
    }
    LGKM0();
    BAR();
    // ---- MFMA phase
#pragma unroll
    for (int ks = 0; ks < 2; ++ks) {
      short8 a1[4], a2[4], b1[4], b2[4];
#pragma unroll
      for (int mi = 0; mi < 4; ++mi) {
        int r = wr * 64 + mi * 16 + (lane & 15);
        int slot = (ks * 4 + (lane >> 4)) ^ (r & 7);
        a1[mi] = *(const short8*)(A1 + r * 128 + slot * 16);
        a2[mi] = *(const short8*)(A2 + r * 128 + slot * 16);
      }
#pragma unroll
      for (int nj = 0; nj < 4; ++nj) {
        int c = wc * 64 + nj * 16 + (lane & 15);
        int slot = (ks * 4 + (lane >> 4)) ^ (c & 7);
        b1[nj] = *(const short8*)(B1 + c * 128 + slot * 16);
        b2[nj] = *(const short8*)(B2 + c * 128 + slot * 16);
      }
#pragma unroll
      for (int mi = 0; mi < 4; ++mi)
#pragma unroll
        for (int nj = 0; nj < 4; ++nj) {
          acc1[mi][nj] = __builtin_amdgcn_mfma_f32_16x16x32_bf16(a1[mi], b1[nj], acc1[mi][nj], 0, 0, 0);
          acc2[mi][nj] = __builtin_amdgcn_mfma_f32_16x16x32_bf16(a2[mi], b2[nj], acc2[mi][nj], 0, 0, 0);
        }
    }
    BAR();
    if (kt < 15) {
#pragma unroll
      for (int i = 0; i < 4; ++i) {
        int q = wid * 4 + i;
        int r = q * 8 + (lane >> 3);
        int sl = (lane & 7) ^ (r & 7);
        __builtin_amdgcn_global_load_lds((gptr1)(P1b + (size_t)(d0 + r) * NN + k0 + 64 + sl * 8),
                                         (lptr3)(B1 + q * 1024), 16, 0, 0);
        __builtin_amdgcn_global_load_lds((gptr1)(P2b + (size_t)(d0 + r) * NN + k0 + 64 + sl * 8),
                                         (lptr3)(B2 + q * 1024), 16, 0, 0);
      }
      pc = pn;
    }
    __builtin_amdgcn_sched_barrier(0);
  }
  // ---- epilogue: combine dirs, bias, relu, residual; write pre-LN f32
#pragma unroll
  for (int mi = 0; mi < 4; ++mi) {
#pragma unroll
    for (int rr = 0; rr < 4; ++rr) {
      int n = n0 + wr * 64 + mi * 16 + (lane >> 4) * 4 + rr;
      float i1 = invc[((size_t)b * NN + n) * 2 + 0];
      float i2 = invc[((size_t)b * NN + n) * 2 + 1];
      const float* hrow = hid + ((size_t)b * NN + n) * ND;
      float* orow = out + ((size_t)b * NN + n) * ND;
#pragma unroll
      for (int nj = 0; nj < 4; ++nj) {
        int d = d0 + wc * 64 + nj * 16 + (lane & 15);
        float v = acc1[mi][nj][rr] * i1 + acc2[mi][nj][rr] * i2 + bias[d];
        v = fmaxf(v, 0.f);
        orow[d] = v + hrow[d];
      }
    }
  }
}

// ---------------- k_ln: in-place rowwise LayerNorm on d_out ------------------
__global__ void k_ln(float* __restrict__ out, const float* __restrict__ gamma,
                     const float* __restrict__ beta) {
  int row = blockIdx.x * 4 + (threadIdx.x >> 6);
  int lane = threadIdx.x & 63;
  float* p = out + (size_t)row * ND;
  float4 x0 = *(const float4*)(p + lane * 4);
  float4 x1 = *(const float4*)(p + 256 + lane * 4);
  float s = x0.x + x0.y + x0.z + x0.w + x1.x + x1.y + x1.z + x1.w;
#pragma unroll
  for (int o = 32; o; o >>= 1) s += __shfl_xor(s, o);
  float mu = s * (1.0f / 512.0f);
  float d0x = x0.x - mu, d0y = x0.y - mu, d0z = x0.z - mu, d0w = x0.w - mu;
  float d1x = x1.x - mu, d1y = x1.y - mu, d1z = x1.z - mu, d1w = x1.w - mu;
  float v = d0x * d0x + d0y * d0y + d0z * d0z + d0w * d0w
          + d1x * d1x + d1y * d1y + d1z * d1z + d1w * d1w;
#pragma unroll
  for (int o = 32; o; o >>= 1) v += __shfl_xor(v, o);
  float rs = rsqrtf(v * (1.0f / 512.0f) + 1e-5f);
  float4 g0 = *(const float4*)(gamma + lane * 4);
  float4 g1 = *(const float4*)(gamma + 256 + lane * 4);
  float4 b0 = *(const float4*)(beta + lane * 4);
  float4 b1 = *(const float4*)(beta + 256 + lane * 4);
  float4 y0, y1;
  y0.x = d0x * rs * g0.x + b0.x; y0.y = d0y * rs * g0.y + b0.y;
  y0.z = d0z * rs * g0.z + b0.z; y0.w = d0w * rs * g0.w + b0.w;
  y1.x = d1x * rs * g1.x + b1.x; y1.y = d1y * rs * g1.y + b1.y;
  y1.z = d1z * rs * g1.z + b1.z; y1.w = d1w * rs * g1.w + b1.w;
  *(float4*)(p + lane * 4) = y0;
  *(float4*)(p + 256 + lane * 4) = y1;
}

extern "C" void kernel_launch(void* const* d_in, const int* in_sizes, int n_in,
                              void* d_out, int out_size, void* d_ws, size_t ws_size,
                              hipStream_t stream) {
  (void)in_sizes; (void)n_in; (void)out_size; (void)ws_size;
  const int*   adj   = (const int*)d_in[0];
  const float* hid   = (const float*)d_in[1];
  const float* W     = (const float*)d_in[2];
  const float* bias  = (const float*)d_in[3];
  const float* gamma = (const float*)d_in[4];
  const float* beta  = (const float*)d_in[5];
  float* out = (float*)d_out;

  char* ws = (char*)d_ws;
  unsigned short* WT     = (unsigned short*)ws;                 // 1 MiB
  unsigned short* Pt1    = (unsigned short*)(ws + 1048576);     // 16 MiB
  unsigned short* Pt2    = (unsigned short*)(ws + 17825792);    // 16 MiB
  unsigned*       packed = (unsigned*)(ws + 34603008);          // 4 MiB
  float*          invc   = (float*)(ws + 38797312);             // 128 KiB

  k_wt  <<<dim3(16, 8), 256, 0, stream>>>(W, WT);
  k_pack<<<1024, 256, 0, stream>>>(adj, packed, invc);
  k_pre <<<512, 256, 0, stream>>>(hid, WT, Pt1, Pt2);
  k_main<<<512, 256, 0, stream>>>(packed, Pt1, Pt2, invc, bias, hid, out);
  k_ln  <<<4096, 256, 0, stream>>>(out, gamma, beta);
}